// Round 7
// baseline (686.734 us; speedup 1.0000x reference)
//
#include <hip/hip_runtime.h>
#include <math.h>

// Problem constants: B=16, T=4096, D=512, N=9, K=1024, d=8
#define ROWS   65536

// ---- workspace float offsets ----
#define WS_WPAD 0          // W_in_all padded [512][96]: col cc=8i+c at (cc/9)*12+cc%9
#define WS_WOUT 49152      // W_out_all [72][512], row jr = 8j+a
#define WS_CBT  86016      // normalized codebooks transposed [9][8][1024]
#define WS_SC   159744     // sum(cb_n^2) [9][1024]
#define WS_M    168960     // M[j][i][a*8+b] = sum_t Wout[j][a][t]*Win[i][t][b]
#define WS_CACC 174144     // [9][8]: sum_{j<i} out_b_j @ W_in_i
#define WS_SOB  174216     // [512]: sum_j out_b_j
#define WS_LOSS 174728     // double accumulator (8B aligned)

// ---- output float offsets ----
#define OUT_CODES 33554432
#define OUT_LAT   34144256
#define OUT_CLOSS 38862848
#define OUT_CBLOSS 38862849

// ---- fused-kernel LDS float offsets (total 19880 floats = 79.5 KB) ----
#define SM_AST   0        // [32][132] gemm_in A-tile (phase 1), k-row k at slot ((k&3)<<3)|(k>>2)
#define SM_BS    4224     // [32][96]  gemm_in B-tile (phase 1)
#define SM_P     0        // [128][72] latents pre-stage (phase 2; overlaps AsT/Bs)
#define SM_QLT   0        // [72][128] Q transposed (phase 3; overlaps P)
#define SM_REG2  9216     // zen [4][32][12] (phase 2) / Ws [72][132] skewed (phase 3)
#define SM_WIN   10752    // [4][32][2] per-wave pass-A winners (inside Ws region, phase-2 only)
#define SM_CODES 18720    // [128][9]
#define SM_WARR  19872    // [8]

__device__ __forceinline__ int pcol(int cc){ return (cc/9)*12 + (cc%9); }

// ---------------- prep1: weight-norm + codebook normalize ----------------
__global__ __launch_bounds__(256) void prep1(const float* __restrict__ in_v,
    const float* __restrict__ in_g, const float* __restrict__ out_v,
    const float* __restrict__ out_g, const float* __restrict__ out_b,
    const float* __restrict__ cb, float* __restrict__ ws)
{
    int t = blockIdx.x*256 + threadIdx.x;
    if (t < 9216) {
        int i = t >> 10, k = t & 1023;
        const float* p = cb + (i*1024 + k)*8;
        float v[8]; float ssq = 0.f;
        #pragma unroll
        for (int c=0;c<8;c++){ v[c]=p[c]; ssq = fmaf(v[c],v[c],ssq); }
        float den = fmaxf(sqrtf(ssq), 1e-12f);
        float sc = 0.f;
        #pragma unroll
        for (int c=0;c<8;c++){ float cn = v[c]/den; ws[WS_CBT + (i*8+c)*1024 + k] = cn; sc = fmaf(cn,cn,sc); }
        ws[WS_SC + i*1024 + k] = sc;
    } else if (t < 13824) {
        int r = t - 9216; int j = r >> 9, tt = r & 511;
        float v[8]; float ssq = 0.f;
        #pragma unroll
        for (int a=0;a<8;a++){ v[a]=out_v[(j*8+a)*512+tt]; ssq=fmaf(v[a],v[a],ssq); }
        float den = fmaxf(sqrtf(ssq), 1e-12f);
        float g = out_g[j*512+tt];
        #pragma unroll
        for (int a=0;a<8;a++) ws[WS_WOUT + (j*8+a)*512 + tt] = g*v[a]/den;
    } else if (t < 18432) {
        int r = t - 13824;
        int w = r >> 6, l = r & 63;
        int i = w >> 3, c = w & 7;
        float v[8]; float ssq = 0.f;
        #pragma unroll
        for (int u=0;u<8;u++){ v[u] = in_v[(i*512 + l*8+u)*8 + c]; ssq = fmaf(v[u],v[u],ssq); }
        #pragma unroll
        for (int off=1; off<64; off<<=1) ssq += __shfl_xor(ssq, off, 64);
        float den = fmaxf(sqrtf(ssq), 1e-12f);
        float g = in_g[i*8+c];
        int pc = pcol(i*8+c);
        #pragma unroll
        for (int u=0;u<8;u++) ws[WS_WPAD + (l*8+u)*96 + pc] = g*v[u]/den;
    } else if (t < 18944) {
        int tt = t - 18432;
        float s = 0.f;
        for (int j=0;j<9;j++) s += out_b[j*512+tt];
        ws[WS_SOB + tt] = s;
    } else if (t == 18944) {
        *(double*)&ws[WS_LOSS] = 0.0;
    }
}

// ---------------- prep2: cross-term tables M and Cacc ----------------
__global__ __launch_bounds__(256) void prep2(const float* __restrict__ out_b,
                                             float* __restrict__ ws)
{
    int g = blockIdx.x*256 + threadIdx.x;
    if (g < 41472) {
        int oi = g >> 3, part = g & 7;
        int j = oi / 576; int rem = oi % 576; int i = rem >> 6; int ab = rem & 63;
        int a = ab >> 3, b = ab & 7;
        int pc = pcol(i*8+b);
        const float* wo = ws + WS_WOUT + (j*8+a)*512 + part*64;
        const float* wp = ws + WS_WPAD + (part*64)*96 + pc;
        float s = 0.f;
        #pragma unroll
        for (int u=0; u<16; u++) {
            float4 w4 = *(const float4*)(wo + u*4);
            s = fmaf(w4.x, wp[(u*4+0)*96], s);
            s = fmaf(w4.y, wp[(u*4+1)*96], s);
            s = fmaf(w4.z, wp[(u*4+2)*96], s);
            s = fmaf(w4.w, wp[(u*4+3)*96], s);
        }
        #pragma unroll
        for (int off=1; off<8; off<<=1) s += __shfl_xor(s, off, 64);
        if (part == 0) ws[WS_M + oi] = s;   // oi == (j*9+i)*64 + ab
    } else if (g < 42048) {
        int r = g - 41472;
        int oi = r >> 3, part = r & 7;
        int i = oi >> 3, b = oi & 7;
        int pc = pcol(i*8+b);
        float s = 0.f;
        for (int u=0; u<64; u++) {
            int tt = part*64 + u;
            float bb = 0.f;
            for (int j=0;j<i;j++) bb += out_b[j*512+tt];
            s = fmaf(bb, ws[WS_WPAD + tt*96+pc], s);
        }
        #pragma unroll
        for (int off=1; off<8; off<<=1) s += __shfl_xor(s, off, 64);
        if (part == 0) ws[WS_CACC + oi] = s;
    }
}

// ---------------- fused_all: gemm_in -> 9 stages -> gemm_out, one block = 128 rows ----
__global__ __launch_bounds__(256, 2) void fused_all(
    const float* __restrict__ z, const float* __restrict__ in_b,
    const float* __restrict__ cbooks, float* __restrict__ ws, float* __restrict__ out)
{
    __shared__ __align__(16) float smem[19880];
    int tid = threadIdx.x;
    int brow = blockIdx.x * 128;

    // ============ phase 1: gemm_in (identical numerics) -> P in LDS ============
    // AsT k-slot swizzle: row k stored at slot s(k)=((k&3)<<3)|(k>>2) so the
    // transpose-scatter writes hit banks 4*kq+rr (2-way, free) instead of 4-way.
    {
        float* AsT = smem + SM_AST;   // [slot][row], stride 132 (528B = 33*16, b128-aligned)
        float* Bs  = smem + SM_BS;    // [k][96]
        int tr = tid & 31, tc = tid >> 5;
        float acc[4][9];
        #pragma unroll
        for (int r=0;r<4;r++){
            #pragma unroll
            for(int c=0;c<9;c++) acc[r][c]=0.f;
        }
        int kq = tid & 7, rr = tid >> 3;
        for (int kk=0; kk<16; kk++) {
            #pragma unroll
            for (int p=0;p<4;p++){
                int row = rr + p*32;
                float4 a = *(const float4*)(z + (size_t)(brow+row)*512 + kk*32 + kq*4);
                // k = 4*kq+u  ->  slot = (u<<3)|kq
                AsT[(kq     )*132 + row] = a.x;
                AsT[(kq +  8)*132 + row] = a.y;
                AsT[(kq + 16)*132 + row] = a.z;
                AsT[(kq + 24)*132 + row] = a.w;
            }
            #pragma unroll
            for (int p=0;p<3;p++){
                int idx = p*256 + tid;
                *(float4*)(Bs + idx*4) = *(const float4*)(ws + WS_WPAD + kk*32*96 + idx*4);
            }
            __syncthreads();
            #pragma unroll 4
            for (int k=0;k<32;k++){
                int sk = ((k&3)<<3) | (k>>2);
                float4 a  = *(const float4*)(AsT + sk*132 + tr*4);
                float4 b0 = *(const float4*)(Bs + k*96 + tc*12);
                float4 b1 = *(const float4*)(Bs + k*96 + tc*12 + 4);
                float  b8 = Bs[k*96 + tc*12 + 8];
                float av[4] = {a.x,a.y,a.z,a.w};
                float bv[9] = {b0.x,b0.y,b0.z,b0.w,b1.x,b1.y,b1.z,b1.w,b8};
                #pragma unroll
                for (int r=0;r<4;r++){
                    #pragma unroll
                    for (int c=0;c<9;c++) acc[r][c] = fmaf(av[r], bv[c], acc[r][c]);
                }
            }
            __syncthreads();
        }
        // staging dead -> write P (overlaps AsT region)
        float* P = smem + SM_P;
        #pragma unroll
        for (int c=0;c<9;c++){
            int cc = tc*9+c;
            float bias = in_b[cc];
            #pragma unroll
            for (int r=0;r<4;r++){
                int rl = tr*4 + r;
                P[rl*72 + cc] = acc[r][c] + bias;
            }
        }
        __syncthreads();
    }

    // ============ phase 2: 9 quantizer stages (wave-autonomous) ============
    // Scan restructured to TWO PASSES of 8 codes/lane so the codebook block
    // (64 regs) + live state fits under the 128-VGPR allocator boundary ->
    // no rematerialized global loads inside the 32-row scan (r3-r5 lesson).
    int w  = tid >> 6;
    int l  = tid & 63;
    int rowhalf = l >> 1;
    int ah = l & 1;
    int wrow = brow + w*32;
    float* P = smem + SM_P;
    float* zen_w = smem + SM_REG2 + w*384;
    float* win_w = smem + SM_WIN + w*64;    // [32][2] pass-A winners (wave-private)
    float* codes_lds = smem + SM_CODES;     // [row][9]

    float lacc = 0.f;

    #pragma unroll 1
    for (int i=0; i<9; i++){
        // ---- Phase A: ze for own row (pair-redundant, exact op order) ----
        int row = wrow + rowhalf;
        int rib = w*32 + rowhalf;
        float* lat = out + OUT_LAT + (size_t)row*72 + i*8;
        float4 p0 = *(const float4*)(P + rib*72 + i*8);
        float4 p1 = *(const float4*)(P + rib*72 + i*8 + 4);
        float ze[8] = {p0.x,p0.y,p0.z,p0.w,p1.x,p1.y,p1.z,p1.w};
        #pragma unroll
        for (int b=0;b<8;b++) ze[b] -= ws[WS_CACC + i*8 + b];
        #pragma unroll 1
        for (int j=0;j<i;j++){
            int kj = (int)codes_lds[rib*9 + j];
            const float* qp = cbooks + (size_t)(j*1024+kj)*8;
            float4 q0 = *(const float4*)(qp);
            float4 q1 = *(const float4*)(qp+4);
            float qa[8] = {q0.x,q0.y,q0.z,q0.w,q1.x,q1.y,q1.z,q1.w};
            const float* M = ws + WS_M + (j*9+i)*64;
            #pragma unroll
            for (int a=0;a<8;a++){
                #pragma unroll
                for (int b=0;b<8;b++) ze[b] = fmaf(-qa[a], M[a*8+b], ze[b]);
            }
        }
        float ssq = 0.f;
        #pragma unroll
        for (int c=0;c<8;c++) ssq = fmaf(ze[c],ze[c],ssq);
        float den = fmaxf(sqrtf(ssq), 1e-12f);
        float rden = 1.0f/den;
        float zen[8];
        #pragma unroll
        for (int c=0;c<8;c++) zen[c] = ze[c]*rden;
        if (ah == 0){
            float4 n0 = {zen[0],zen[1],zen[2],zen[3]};
            float4 n1 = {zen[4],zen[5],zen[6],zen[7]};
            *(float4*)(zen_w + rowhalf*12)     = n0;
            *(float4*)(zen_w + rowhalf*12 + 4) = n1;
        } else {
            float4 z0 = {ze[0],ze[1],ze[2],ze[3]};
            float4 z1 = {ze[4],ze[5],ze[6],ze[7]};
            *(float4*)(lat)   = z0;
            *(float4*)(lat+4) = z1;
        }

        // ---- Phase B: two passes, 8 codes/lane; winner parked in LDS ----
        int ksave = 0;
        #pragma unroll 1
        for (int p=0; p<2; p++){
            int kbp = p*512 + l*8;
            const float* cbb = ws + WS_CBT + i*8192 + kbp;
            float4 cbr[2][8];
            #pragma unroll
            for (int c=0;c<8;c++){
                cbr[0][c] = *(const float4*)(cbb + c*1024);
                cbr[1][c] = *(const float4*)(cbb + c*1024 + 4);
            }
            float4 s0 = *(const float4*)(ws + WS_SC + i*1024 + kbp);
            float4 s1 = *(const float4*)(ws + WS_SC + i*1024 + kbp + 4);
            float4 hs0, hs1;
            hs0.x = s0.x*-0.5f; hs0.y = s0.y*-0.5f; hs0.z = s0.z*-0.5f; hs0.w = s0.w*-0.5f;
            hs1.x = s1.x*-0.5f; hs1.y = s1.y*-0.5f; hs1.z = s1.z*-0.5f; hs1.w = s1.w*-0.5f;

            #pragma unroll 2
            for (int rr=0; rr<32; rr++){
                float4 zv0 = *(const float4*)(zen_w + rr*12);
                float4 zv1 = *(const float4*)(zen_w + rr*12 + 4);
                float zr[8] = {zv0.x,zv0.y,zv0.z,zv0.w,zv1.x,zv1.y,zv1.z,zv1.w};
                float d0=hs0.x, d1=hs0.y, d2=hs0.z, d3=hs0.w;
                float d4=hs1.x, d5=hs1.y, d6=hs1.z, d7=hs1.w;
                #pragma unroll
                for (int c=0;c<8;c++){
                    d0 = fmaf(zr[c], cbr[0][c].x, d0);
                    d1 = fmaf(zr[c], cbr[0][c].y, d1);
                    d2 = fmaf(zr[c], cbr[0][c].z, d2);
                    d3 = fmaf(zr[c], cbr[0][c].w, d3);
                    d4 = fmaf(zr[c], cbr[1][c].x, d4);
                    d5 = fmaf(zr[c], cbr[1][c].y, d5);
                    d6 = fmaf(zr[c], cbr[1][c].z, d6);
                    d7 = fmaf(zr[c], cbr[1][c].w, d7);
                }
                float bv = d0; int rel = 0;
                bool c1 = d1 > bv; rel = c1?1:rel; bv = c1?d1:bv;
                bool c2 = d2 > bv; rel = c2?2:rel; bv = c2?d2:bv;
                bool c3 = d3 > bv; rel = c3?3:rel; bv = c3?d3:bv;
                bool c4 = d4 > bv; rel = c4?4:rel; bv = c4?d4:bv;
                bool c5 = d5 > bv; rel = c5?5:rel; bv = c5?d5:bv;
                bool c6 = d6 > bv; rel = c6?6:rel; bv = c6?d6:bv;
                bool c7 = d7 > bv; rel = c7?7:rel; bv = c7?d7:bv;

                float wm = bv;
                #pragma unroll
                for (int off=1; off<64; off<<=1) wm = fmaxf(wm, __shfl_xor(wm, off, 64));
                unsigned long long msk = __ballot(bv == wm);
                int ln = __ffsll((long long)msk) - 1;   // lowest lane with max = lowest k
                int kwin = __shfl(kbp + rel, ln, 64);
                if (p == 0){
                    if (l == 0){
                        float2 pw = {wm, (float)kwin};
                        *(float2*)(win_w + rr*2) = pw;
                    }
                } else {
                    float2 pw = *(const float2*)(win_w + rr*2);
                    bool keepA = (pw.x >= wm);          // ties -> pass A (lower k)
                    wm   = keepA ? pw.x : wm;
                    kwin = keepA ? (int)pw.y : kwin;
                    ksave = (rowhalf == rr) ? kwin : ksave;
                }
            }
        }

        // ---- epilogue: pair splits loss (ah=0) and writes (ah=1) ----
        if (ah == 0){
            const float* qp = cbooks + (size_t)(i*1024+ksave)*8;
            float4 q0 = *(const float4*)(qp);
            float4 q1 = *(const float4*)(qp+4);
            float e0 = ze[0]-q0.x, e1 = ze[1]-q0.y, e2 = ze[2]-q0.z, e3 = ze[3]-q0.w;
            float e4 = ze[4]-q1.x, e5 = ze[5]-q1.y, e6 = ze[6]-q1.z, e7 = ze[7]-q1.w;
            lacc = fmaf(e0,e0,lacc); lacc = fmaf(e1,e1,lacc);
            lacc = fmaf(e2,e2,lacc); lacc = fmaf(e3,e3,lacc);
            lacc = fmaf(e4,e4,lacc); lacc = fmaf(e5,e5,lacc);
            lacc = fmaf(e6,e6,lacc); lacc = fmaf(e7,e7,lacc);
        } else {
            out[OUT_CODES + (size_t)row*9 + i] = (float)ksave;
            codes_lds[rib*9 + i] = (float)ksave;
        }
    }

    // ---- loss reduction: one atomic per block ----
    {
        float* warr = smem + SM_WARR;
        #pragma unroll
        for (int off=1; off<64; off<<=1) lacc += __shfl_xor(lacc, off, 64);
        if ((tid & 63)==0) warr[w] = lacc;
        __syncthreads();
        if (tid==0){
            double bs = (double)warr[0]+(double)warr[1]+(double)warr[2]+(double)warr[3];
            atomicAdd((double*)&ws[WS_LOSS], bs);
        }
    }

    // ============ phase 3: gemm_out (identical compute), Q from codes_lds ============
    __syncthreads();   // P dead; QLT/Ws regions free
    {
        float* QLT = smem + SM_QLT;   // [k=72][row=128]
        float* Ws  = smem + SM_REG2;  // [72][132]
        if (tid < 128){
            for (int j=0;j<9;j++){
                int kj = (int)codes_lds[tid*9 + j];
                const float* qp = cbooks + (size_t)(j*1024+kj)*8;
                float4 q0 = *(const float4*)qp;
                float4 q1 = *(const float4*)(qp+4);
                QLT[(j*8+0)*128 + tid] = q0.x;
                QLT[(j*8+1)*128 + tid] = q0.y;
                QLT[(j*8+2)*128 + tid] = q0.z;
                QLT[(j*8+3)*128 + tid] = q0.w;
                QLT[(j*8+4)*128 + tid] = q1.x;
                QLT[(j*8+5)*128 + tid] = q1.y;
                QLT[(j*8+6)*128 + tid] = q1.z;
                QLT[(j*8+7)*128 + tid] = q1.w;
            }
        }
        int tc = tid & 15, tr = tid >> 4;    // rows tr*8..+7, cols tc*8..+7 per chunk
        int aoff = tr*8;
        int boff = tc*8 + (tc>>3)*4;
        for (int cc=0; cc<4; cc++){
            __syncthreads();
            #pragma unroll
            for (int p=0;p<9;p++){
                int idx = p*256 + tid;
                int jr = idx >> 5; int cq = idx & 31;
                float4 wv = *(const float4*)(ws + WS_WOUT + jr*512 + cc*128 + cq*4);
                *(float4*)(Ws + jr*132 + cq*4 + (cq>>4)*4) = wv;
            }
            __syncthreads();
            float acc[8][8];
            #pragma unroll
            for (int r=0;r<8;r++){
                #pragma unroll
                for (int c=0;c<8;c++) acc[r][c]=0.f;
            }
            #pragma unroll 2
            for (int k=0;k<72;k++){
                float4 a0 = *(const float4*)(QLT + k*128 + aoff);
                float4 a1 = *(const float4*)(QLT + k*128 + aoff + 4);
                float4 b0 = *(const float4*)(Ws + k*132 + boff);
                float4 b1 = *(const float4*)(Ws + k*132 + boff + 4);
                float av[8] = {a0.x,a0.y,a0.z,a0.w,a1.x,a1.y,a1.z,a1.w};
                float bw[8] = {b0.x,b0.y,b0.z,b0.w,b1.x,b1.y,b1.z,b1.w};
                #pragma unroll
                for (int r=0;r<8;r++){
                    #pragma unroll
                    for (int c=0;c<8;c++) acc[r][c] = fmaf(av[r], bw[c], acc[r][c]);
                }
            }
            float4 s0 = *(const float4*)(ws + WS_SOB + cc*128 + tc*8);
            float4 s1 = *(const float4*)(ws + WS_SOB + cc*128 + tc*8 + 4);
            #pragma unroll
            for (int r=0;r<8;r++){
                int row = brow + tr*8 + r;
                float4 o0 = {acc[r][0]+s0.x, acc[r][1]+s0.y, acc[r][2]+s0.z, acc[r][3]+s0.w};
                float4 o1 = {acc[r][4]+s1.x, acc[r][5]+s1.y, acc[r][6]+s1.z, acc[r][7]+s1.w};
                *(float4*)(out + (size_t)row*512 + cc*128 + tc*8)     = o0;
                *(float4*)(out + (size_t)row*512 + cc*128 + tc*8 + 4) = o1;
            }
        }
    }
}

// ---------------- finalize: loss scalars ----------------
__global__ void finalize(const float* __restrict__ ws, float* __restrict__ out)
{
    if (threadIdx.x == 0){
        double L = *(const double*)(ws + WS_LOSS);
        float lv = (float)(L * (1.0/524288.0));   // / (B*T*d)
        out[OUT_CLOSS]  = lv;
        out[OUT_CBLOSS] = lv;
    }
}

extern "C" void kernel_launch(void* const* d_in, const int* in_sizes, int n_in,
                              void* d_out, int out_size, void* d_ws, size_t ws_size,
                              hipStream_t stream) {
    const float* z     = (const float*)d_in[0];
    const float* in_v  = (const float*)d_in[1];
    const float* in_g  = (const float*)d_in[2];
    const float* in_b  = (const float*)d_in[3];
    const float* out_v = (const float*)d_in[4];
    const float* out_g = (const float*)d_in[5];
    const float* out_b = (const float*)d_in[6];
    const float* cb    = (const float*)d_in[7];
    float* out = (float*)d_out;
    float* ws  = (float*)d_ws;

    prep1<<<75, 256, 0, stream>>>(in_v, in_g, out_v, out_g, out_b, cb, ws);
    prep2<<<165, 256, 0, stream>>>(out_b, ws);
    fused_all<<<512, 256, 0, stream>>>(z, in_b, cb, ws, out);
    finalize<<<1, 64, 0, stream>>>(ws, out);
}

// Round 8
// 585.498 us; speedup vs baseline: 1.1729x; 1.1729x over previous
//
#include <hip/hip_runtime.h>
#include <math.h>

// Problem constants: B=16, T=4096, D=512, N=9, K=1024, d=8
#define ROWS   65536

// ---- workspace float offsets ----
#define WS_WPAD 0          // W_in_all padded [512][96]: col cc=8i+c at (cc/9)*12+cc%9
#define WS_WOUT 49152      // W_out_all [72][512], row jr = 8j+a
#define WS_CBT  86016      // normalized codebooks transposed [9][8][1024]
#define WS_SC   159744     // sum(cb_n^2) [9][1024]
#define WS_M    168960     // M[j][i][a*8+b] = sum_t Wout[j][a][t]*Win[i][t][b]
#define WS_CACC 174144     // [9][8]: sum_{j<i} out_b_j @ W_in_i
#define WS_SOB  174216     // [512]: sum_j out_b_j
#define WS_LOSS 174728     // double accumulator (8B aligned)

// ---- output float offsets ----
#define OUT_CODES 33554432
#define OUT_LAT   34144256
#define OUT_CLOSS 38862848
#define OUT_CBLOSS 38862849

// ---- fused-kernel LDS float offsets (total 19880 floats = 79.5 KB) ----
#define SM_AST   0        // [32][132] gemm_in A-tile (phase 1), k-row k at slot ((k&3)<<3)|(k>>2)
#define SM_BS    4224     // [32][96]  gemm_in B-tile (phase 1)
#define SM_P     0        // [128][72] latents pre-stage (phase 2; overlaps AsT/Bs)
#define SM_QLT   0        // [72][128] Q transposed (phase 3; overlaps P)
#define SM_REG2  9216     // zen [4][32][12] (phase 2) / Ws [72][132] skewed (phase 3)
#define SM_CODES 18720    // [128][9]
#define SM_WARR  19872    // [8]

typedef float v2f __attribute__((ext_vector_type(2)));
__device__ __forceinline__ v2f fma2(v2f a, v2f b, v2f c){
    return __builtin_elementwise_fma(a, b, c);   // -> v_pk_fma_f32 (2x IEEE fma)
}

__device__ __forceinline__ int pcol(int cc){ return (cc/9)*12 + (cc%9); }

// ---------------- prep1: weight-norm + codebook normalize ----------------
__global__ __launch_bounds__(256) void prep1(const float* __restrict__ in_v,
    const float* __restrict__ in_g, const float* __restrict__ out_v,
    const float* __restrict__ out_g, const float* __restrict__ out_b,
    const float* __restrict__ cb, float* __restrict__ ws)
{
    int t = blockIdx.x*256 + threadIdx.x;
    if (t < 9216) {
        int i = t >> 10, k = t & 1023;
        const float* p = cb + (i*1024 + k)*8;
        float v[8]; float ssq = 0.f;
        #pragma unroll
        for (int c=0;c<8;c++){ v[c]=p[c]; ssq = fmaf(v[c],v[c],ssq); }
        float den = fmaxf(sqrtf(ssq), 1e-12f);
        float sc = 0.f;
        #pragma unroll
        for (int c=0;c<8;c++){ float cn = v[c]/den; ws[WS_CBT + (i*8+c)*1024 + k] = cn; sc = fmaf(cn,cn,sc); }
        ws[WS_SC + i*1024 + k] = sc;
    } else if (t < 13824) {
        int r = t - 9216; int j = r >> 9, tt = r & 511;
        float v[8]; float ssq = 0.f;
        #pragma unroll
        for (int a=0;a<8;a++){ v[a]=out_v[(j*8+a)*512+tt]; ssq=fmaf(v[a],v[a],ssq); }
        float den = fmaxf(sqrtf(ssq), 1e-12f);
        float g = out_g[j*512+tt];
        #pragma unroll
        for (int a=0;a<8;a++) ws[WS_WOUT + (j*8+a)*512 + tt] = g*v[a]/den;
    } else if (t < 18432) {
        int r = t - 13824;
        int w = r >> 6, l = r & 63;
        int i = w >> 3, c = w & 7;
        float v[8]; float ssq = 0.f;
        #pragma unroll
        for (int u=0;u<8;u++){ v[u] = in_v[(i*512 + l*8+u)*8 + c]; ssq = fmaf(v[u],v[u],ssq); }
        #pragma unroll
        for (int off=1; off<64; off<<=1) ssq += __shfl_xor(ssq, off, 64);
        float den = fmaxf(sqrtf(ssq), 1e-12f);
        float g = in_g[i*8+c];
        int pc = pcol(i*8+c);
        #pragma unroll
        for (int u=0;u<8;u++) ws[WS_WPAD + (l*8+u)*96 + pc] = g*v[u]/den;
    } else if (t < 18944) {
        int tt = t - 18432;
        float s = 0.f;
        for (int j=0;j<9;j++) s += out_b[j*512+tt];
        ws[WS_SOB + tt] = s;
    } else if (t == 18944) {
        *(double*)&ws[WS_LOSS] = 0.0;
    }
}

// ---------------- prep2: cross-term tables M and Cacc ----------------
__global__ __launch_bounds__(256) void prep2(const float* __restrict__ out_b,
                                             float* __restrict__ ws)
{
    int g = blockIdx.x*256 + threadIdx.x;
    if (g < 41472) {
        int oi = g >> 3, part = g & 7;
        int j = oi / 576; int rem = oi % 576; int i = rem >> 6; int ab = rem & 63;
        int a = ab >> 3, b = ab & 7;
        int pc = pcol(i*8+b);
        const float* wo = ws + WS_WOUT + (j*8+a)*512 + part*64;
        const float* wp = ws + WS_WPAD + (part*64)*96 + pc;
        float s = 0.f;
        #pragma unroll
        for (int u=0; u<16; u++) {
            float4 w4 = *(const float4*)(wo + u*4);
            s = fmaf(w4.x, wp[(u*4+0)*96], s);
            s = fmaf(w4.y, wp[(u*4+1)*96], s);
            s = fmaf(w4.z, wp[(u*4+2)*96], s);
            s = fmaf(w4.w, wp[(u*4+3)*96], s);
        }
        #pragma unroll
        for (int off=1; off<8; off<<=1) s += __shfl_xor(s, off, 64);
        if (part == 0) ws[WS_M + oi] = s;   // oi == (j*9+i)*64 + ab
    } else if (g < 42048) {
        int r = g - 41472;
        int oi = r >> 3, part = r & 7;
        int i = oi >> 3, b = oi & 7;
        int pc = pcol(i*8+b);
        float s = 0.f;
        for (int u=0; u<64; u++) {
            int tt = part*64 + u;
            float bb = 0.f;
            for (int j=0;j<i;j++) bb += out_b[j*512+tt];
            s = fmaf(bb, ws[WS_WPAD + tt*96+pc], s);
        }
        #pragma unroll
        for (int off=1; off<8; off<<=1) s += __shfl_xor(s, off, 64);
        if (part == 0) ws[WS_CACC + oi] = s;
    }
}

// ---------------- fused_all: gemm_in -> 9 stages -> gemm_out, one block = 128 rows ----
__global__ __launch_bounds__(256, 2) void fused_all(
    const float* __restrict__ z, const float* __restrict__ in_b,
    const float* __restrict__ cbooks, float* __restrict__ ws, float* __restrict__ out)
{
    __shared__ __align__(16) float smem[19880];
    int tid = threadIdx.x;
    int brow = blockIdx.x * 128;

    // ============ phase 1: gemm_in (bit-identical numerics, pk-fma packed) ============
    {
        float* AsT = smem + SM_AST;   // [slot][row], stride 132; k at slot ((k&3)<<3)|(k>>2)
        float* Bs  = smem + SM_BS;    // [k][96]
        int tr = tid & 31, tc = tid >> 5;
        v2f accp[4][4]; float acc8[4];
        #pragma unroll
        for (int r=0;r<4;r++){
            #pragma unroll
            for(int t2=0;t2<4;t2++) accp[r][t2] = (v2f){0.f,0.f};
            acc8[r]=0.f;
        }
        int kq = tid & 7, rr = tid >> 3;
        for (int kk=0; kk<16; kk++) {
            #pragma unroll
            for (int p=0;p<4;p++){
                int row = rr + p*32;
                float4 a = *(const float4*)(z + (size_t)(brow+row)*512 + kk*32 + kq*4);
                AsT[(kq     )*132 + row] = a.x;
                AsT[(kq +  8)*132 + row] = a.y;
                AsT[(kq + 16)*132 + row] = a.z;
                AsT[(kq + 24)*132 + row] = a.w;
            }
            #pragma unroll
            for (int p=0;p<3;p++){
                int idx = p*256 + tid;
                *(float4*)(Bs + idx*4) = *(const float4*)(ws + WS_WPAD + kk*32*96 + idx*4);
            }
            __syncthreads();
            #pragma unroll 4
            for (int k=0;k<32;k++){
                int sk = ((k&3)<<3) | (k>>2);
                float4 a  = *(const float4*)(AsT + sk*132 + tr*4);
                float4 b0 = *(const float4*)(Bs + k*96 + tc*12);
                float4 b1 = *(const float4*)(Bs + k*96 + tc*12 + 4);
                float  b8 = Bs[k*96 + tc*12 + 8];
                float av[4] = {a.x,a.y,a.z,a.w};
                v2f bp[4] = {{b0.x,b0.y},{b0.z,b0.w},{b1.x,b1.y},{b1.z,b1.w}};
                #pragma unroll
                for (int r=0;r<4;r++){
                    v2f ar = {av[r], av[r]};
                    #pragma unroll
                    for (int t2=0;t2<4;t2++) accp[r][t2] = fma2(ar, bp[t2], accp[r][t2]);
                    acc8[r] = fmaf(av[r], b8, acc8[r]);
                }
            }
            __syncthreads();
        }
        float* P = smem + SM_P;
        #pragma unroll
        for (int c=0;c<9;c++){
            int cc = tc*9+c;
            float bias = in_b[cc];
            #pragma unroll
            for (int r=0;r<4;r++){
                int rl = tr*4 + r;
                float val = (c<8) ? accp[r][c>>1][c&1] : acc8[r];
                P[rl*72 + cc] = val + bias;
            }
        }
        __syncthreads();
    }

    // ============ phase 2: 9 quantizer stages (wave-autonomous, single-pass scan) ============
    int w  = tid >> 6;
    int l  = tid & 63;
    int rowhalf = l >> 1;
    int ah = l & 1;
    int wrow = brow + w*32;
    int kb = l*16;
    float* P = smem + SM_P;
    float* zen_w = smem + SM_REG2 + w*384;
    float* codes_lds = smem + SM_CODES;     // [row][9]

    float lacc = 0.f;
    v2f cbp[8][8];   // [pair][dim]: codes kb+2p, kb+2p+1 at dim c
    v2f hp[8];       // -0.5*sc pairs

    #pragma unroll 1
    for (int i=0; i<9; i++){
        // ---- reload this lane's 16 codes + prescaled -0.5*sc (L1/L2-resident) ----
        const float* cbb = ws + WS_CBT + i*8192 + kb;
        #pragma unroll
        for (int c=0;c<8;c++){
            float4 A0 = *(const float4*)(cbb + c*1024);
            float4 A1 = *(const float4*)(cbb + c*1024 + 4);
            float4 A2 = *(const float4*)(cbb + c*1024 + 8);
            float4 A3 = *(const float4*)(cbb + c*1024 + 12);
            cbp[0][c] = (v2f){A0.x,A0.y}; cbp[1][c] = (v2f){A0.z,A0.w};
            cbp[2][c] = (v2f){A1.x,A1.y}; cbp[3][c] = (v2f){A1.z,A1.w};
            cbp[4][c] = (v2f){A2.x,A2.y}; cbp[5][c] = (v2f){A2.z,A2.w};
            cbp[6][c] = (v2f){A3.x,A3.y}; cbp[7][c] = (v2f){A3.z,A3.w};
        }
        {
            const float* scb = ws + WS_SC + i*1024 + kb;
            float4 s0 = *(const float4*)(scb);
            float4 s1 = *(const float4*)(scb + 4);
            float4 s2 = *(const float4*)(scb + 8);
            float4 s3 = *(const float4*)(scb + 12);
            hp[0] = (v2f){s0.x*-0.5f, s0.y*-0.5f}; hp[1] = (v2f){s0.z*-0.5f, s0.w*-0.5f};
            hp[2] = (v2f){s1.x*-0.5f, s1.y*-0.5f}; hp[3] = (v2f){s1.z*-0.5f, s1.w*-0.5f};
            hp[4] = (v2f){s2.x*-0.5f, s2.y*-0.5f}; hp[5] = (v2f){s2.z*-0.5f, s2.w*-0.5f};
            hp[6] = (v2f){s3.x*-0.5f, s3.y*-0.5f}; hp[7] = (v2f){s3.z*-0.5f, s3.w*-0.5f};
        }

        // ---- Phase A: ze for own row (pair-redundant, exact per-element op order) ----
        int row = wrow + rowhalf;
        int rib = w*32 + rowhalf;
        float* lat = out + OUT_LAT + (size_t)row*72 + i*8;
        float4 p0 = *(const float4*)(P + rib*72 + i*8);
        float4 p1 = *(const float4*)(P + rib*72 + i*8 + 4);
        v2f zep[4] = {{p0.x,p0.y},{p0.z,p0.w},{p1.x,p1.y},{p1.z,p1.w}};
        #pragma unroll
        for (int t2=0;t2<4;t2++){
            v2f cp = {ws[WS_CACC + i*8 + 2*t2], ws[WS_CACC + i*8 + 2*t2+1]};
            zep[t2] -= cp;
        }
        #pragma unroll 1
        for (int j=0;j<i;j++){
            int kj = (int)codes_lds[rib*9 + j];
            const float* qp = cbooks + (size_t)(j*1024+kj)*8;
            float4 q0 = *(const float4*)(qp);
            float4 q1 = *(const float4*)(qp+4);
            float qa[8] = {q0.x,q0.y,q0.z,q0.w,q1.x,q1.y,q1.z,q1.w};
            const float* M = ws + WS_M + (j*9+i)*64;
            #pragma unroll
            for (int a=0;a<8;a++){
                float4 m0 = *(const float4*)(M + a*8);
                float4 m1 = *(const float4*)(M + a*8 + 4);
                v2f nqa = {-qa[a], -qa[a]};
                zep[0] = fma2(nqa, (v2f){m0.x,m0.y}, zep[0]);
                zep[1] = fma2(nqa, (v2f){m0.z,m0.w}, zep[1]);
                zep[2] = fma2(nqa, (v2f){m1.x,m1.y}, zep[2]);
                zep[3] = fma2(nqa, (v2f){m1.z,m1.w}, zep[3]);
            }
        }
        float ssq = 0.f;
        #pragma unroll
        for (int c=0;c<8;c++){ float zc = zep[c>>1][c&1]; ssq = fmaf(zc,zc,ssq); }
        float den = fmaxf(sqrtf(ssq), 1e-12f);
        float rden = 1.0f/den;
        v2f rd2 = {rden, rden};
        v2f zenp[4];
        #pragma unroll
        for (int t2=0;t2<4;t2++) zenp[t2] = zep[t2]*rd2;
        if (ah == 0){
            float4 n0 = {zenp[0][0],zenp[0][1],zenp[1][0],zenp[1][1]};
            float4 n1 = {zenp[2][0],zenp[2][1],zenp[3][0],zenp[3][1]};
            *(float4*)(zen_w + rowhalf*12)     = n0;
            *(float4*)(zen_w + rowhalf*12 + 4) = n1;
        } else {
            float4 z0 = {zep[0][0],zep[0][1],zep[1][0],zep[1][1]};
            float4 z1 = {zep[2][0],zep[2][1],zep[3][0],zep[3][1]};
            *(float4*)(lat)   = z0;
            *(float4*)(lat+4) = z1;
        }

        // ---- Phase B: wave scans its 32 rows; lane checks its 16 codes (pk-fma) ----
        int ksave = 0;
        #pragma unroll 2
        for (int rr=0; rr<32; rr++){
            float4 zv0 = *(const float4*)(zen_w + rr*12);
            float4 zv1 = *(const float4*)(zen_w + rr*12 + 4);
            float zr[8] = {zv0.x,zv0.y,zv0.z,zv0.w,zv1.x,zv1.y,zv1.z,zv1.w};
            v2f dp[8];
            #pragma unroll
            for (int p=0;p<8;p++) dp[p] = hp[p];
            #pragma unroll
            for (int c=0;c<8;c++){
                v2f zc = {zr[c], zr[c]};
                #pragma unroll
                for (int p=0;p<8;p++) dp[p] = fma2(zc, cbp[p][c], dp[p]);
            }
            float bv = -3.0e38f; int rel = 0;
            #pragma unroll
            for (int p=0;p<8;p++){
                float de = dp[p][0];
                bool ce = de > bv; rel = ce ? (2*p)   : rel; bv = ce ? de : bv;
                float dohalf = dp[p][1];
                bool co = dohalf > bv; rel = co ? (2*p+1) : rel; bv = co ? dohalf : bv;
            }
            int kfull = kb + rel;
            float wm = bv;
            #pragma unroll
            for (int off=1; off<64; off<<=1) wm = fmaxf(wm, __shfl_xor(wm, off, 64));
            unsigned long long msk = __ballot(bv == wm);
            int ln = __ffsll((long long)msk) - 1;   // lowest lane with max = lowest k
            int kwin = __shfl(kfull, ln, 64);
            ksave = (rowhalf == rr) ? kwin : ksave;
        }

        // ---- epilogue: pair splits loss (ah=0) and writes (ah=1) ----
        if (ah == 0){
            const float* qp = cbooks + (size_t)(i*1024+ksave)*8;
            float4 q0 = *(const float4*)(qp);
            float4 q1 = *(const float4*)(qp+4);
            float e0 = zep[0][0]-q0.x, e1 = zep[0][1]-q0.y, e2 = zep[1][0]-q0.z, e3 = zep[1][1]-q0.w;
            float e4 = zep[2][0]-q1.x, e5 = zep[2][1]-q1.y, e6 = zep[3][0]-q1.z, e7 = zep[3][1]-q1.w;
            lacc = fmaf(e0,e0,lacc); lacc = fmaf(e1,e1,lacc);
            lacc = fmaf(e2,e2,lacc); lacc = fmaf(e3,e3,lacc);
            lacc = fmaf(e4,e4,lacc); lacc = fmaf(e5,e5,lacc);
            lacc = fmaf(e6,e6,lacc); lacc = fmaf(e7,e7,lacc);
        } else {
            out[OUT_CODES + (size_t)row*9 + i] = (float)ksave;
            codes_lds[rib*9 + i] = (float)ksave;
        }
    }

    // ---- loss reduction: one atomic per block ----
    {
        float* warr = smem + SM_WARR;
        #pragma unroll
        for (int off=1; off<64; off<<=1) lacc += __shfl_xor(lacc, off, 64);
        if ((tid & 63)==0) warr[w] = lacc;
        __syncthreads();
        if (tid==0){
            double bs = (double)warr[0]+(double)warr[1]+(double)warr[2]+(double)warr[3];
            atomicAdd((double*)&ws[WS_LOSS], bs);
        }
    }

    // ============ phase 3: gemm_out (bit-identical, pk-fma packed), Q from codes_lds ============
    __syncthreads();   // P dead; QLT/Ws regions free
    {
        float* QLT = smem + SM_QLT;   // [k=72][row=128]
        float* Ws  = smem + SM_REG2;  // [72][132]
        if (tid < 128){
            for (int j=0;j<9;j++){
                int kj = (int)codes_lds[tid*9 + j];
                const float* qp = cbooks + (size_t)(j*1024+kj)*8;
                float4 q0 = *(const float4*)qp;
                float4 q1 = *(const float4*)(qp+4);
                QLT[(j*8+0)*128 + tid] = q0.x;
                QLT[(j*8+1)*128 + tid] = q0.y;
                QLT[(j*8+2)*128 + tid] = q0.z;
                QLT[(j*8+3)*128 + tid] = q0.w;
                QLT[(j*8+4)*128 + tid] = q1.x;
                QLT[(j*8+5)*128 + tid] = q1.y;
                QLT[(j*8+6)*128 + tid] = q1.z;
                QLT[(j*8+7)*128 + tid] = q1.w;
            }
        }
        int tc = tid & 15, tr = tid >> 4;    // rows tr*8..+7, cols tc*8..+7 per chunk
        int aoff = tr*8;
        int boff = tc*8 + (tc>>3)*4;
        for (int cc=0; cc<4; cc++){
            __syncthreads();
            #pragma unroll
            for (int p=0;p<9;p++){
                int idx = p*256 + tid;
                int jr = idx >> 5; int cq = idx & 31;
                float4 wv = *(const float4*)(ws + WS_WOUT + jr*512 + cc*128 + cq*4);
                *(float4*)(Ws + jr*132 + cq*4 + (cq>>4)*4) = wv;
            }
            __syncthreads();
            v2f accp[8][4];
            #pragma unroll
            for (int r=0;r<8;r++){
                #pragma unroll
                for (int t2=0;t2<4;t2++) accp[r][t2] = (v2f){0.f,0.f};
            }
            #pragma unroll 2
            for (int k=0;k<72;k++){
                float4 a0 = *(const float4*)(QLT + k*128 + aoff);
                float4 a1 = *(const float4*)(QLT + k*128 + aoff + 4);
                float4 b0 = *(const float4*)(Ws + k*132 + boff);
                float4 b1 = *(const float4*)(Ws + k*132 + boff + 4);
                float av[8] = {a0.x,a0.y,a0.z,a0.w,a1.x,a1.y,a1.z,a1.w};
                v2f wp[4] = {{b0.x,b0.y},{b0.z,b0.w},{b1.x,b1.y},{b1.z,b1.w}};
                #pragma unroll
                for (int r=0;r<8;r++){
                    v2f ar = {av[r], av[r]};
                    #pragma unroll
                    for (int t2=0;t2<4;t2++) accp[r][t2] = fma2(ar, wp[t2], accp[r][t2]);
                }
            }
            float4 s0 = *(const float4*)(ws + WS_SOB + cc*128 + tc*8);
            float4 s1 = *(const float4*)(ws + WS_SOB + cc*128 + tc*8 + 4);
            #pragma unroll
            for (int r=0;r<8;r++){
                int row = brow + tr*8 + r;
                float4 o0 = {accp[r][0][0]+s0.x, accp[r][0][1]+s0.y, accp[r][1][0]+s0.z, accp[r][1][1]+s0.w};
                float4 o1 = {accp[r][2][0]+s1.x, accp[r][2][1]+s1.y, accp[r][3][0]+s1.z, accp[r][3][1]+s1.w};
                *(float4*)(out + (size_t)row*512 + cc*128 + tc*8)     = o0;
                *(float4*)(out + (size_t)row*512 + cc*128 + tc*8 + 4) = o1;
            }
        }
    }
}

// ---------------- finalize: loss scalars ----------------
__global__ void finalize(const float* __restrict__ ws, float* __restrict__ out)
{
    if (threadIdx.x == 0){
        double L = *(const double*)(ws + WS_LOSS);
        float lv = (float)(L * (1.0/524288.0));   // / (B*T*d)
        out[OUT_CLOSS]  = lv;
        out[OUT_CBLOSS] = lv;
    }
}

extern "C" void kernel_launch(void* const* d_in, const int* in_sizes, int n_in,
                              void* d_out, int out_size, void* d_ws, size_t ws_size,
                              hipStream_t stream) {
    const float* z     = (const float*)d_in[0];
    const float* in_v  = (const float*)d_in[1];
    const float* in_g  = (const float*)d_in[2];
    const float* in_b  = (const float*)d_in[3];
    const float* out_v = (const float*)d_in[4];
    const float* out_g = (const float*)d_in[5];
    const float* out_b = (const float*)d_in[6];
    const float* cb    = (const float*)d_in[7];
    float* out = (float*)d_out;
    float* ws  = (float*)d_ws;

    prep1<<<75, 256, 0, stream>>>(in_v, in_g, out_v, out_g, out_b, cb, ws);
    prep2<<<165, 256, 0, stream>>>(out_b, ws);
    fused_all<<<512, 256, 0, stream>>>(z, in_b, cb, ws, out);
    finalize<<<1, 64, 0, stream>>>(ws, out);
}